// Round 6
// baseline (400.804 us; speedup 1.0000x reference)
//
#include <hip/hip_runtime.h>
#include <hip/hip_bf16.h>

#define FEAT 64
#define CHUNK 8192   // edges per count-role block

typedef __attribute__((ext_vector_type(8))) short bf16x8;
typedef __attribute__((ext_vector_type(4))) float f32x4;
typedef __attribute__((ext_vector_type(2))) float f32x2;

// ---------- bf16 helpers ----------
__device__ __forceinline__ float bflo2f(unsigned int u) {
    union { unsigned int u; float f; } v; v.u = u << 16; return v.f;
}
__device__ __forceinline__ float bfhi2f(unsigned int u) {
    union { unsigned int u; float f; } v; v.u = u & 0xffff0000u; return v.f;
}
__device__ __forceinline__ unsigned short f2bf(float f) {
    union { float f; unsigned int u; } v; v.f = f;
    unsigned int u = v.u;
    u += 0x7fffu + ((u >> 16) & 1u);   // round-to-nearest-even
    return (unsigned short)(u >> 16);
}
__device__ __forceinline__ f32x2 bfpair(unsigned int u) {
    f32x2 r; r.x = bflo2f(u & 0xffffu); r.y = bfhi2f(u); return r;
}

// ---------- 0. prep + degree-count merged: role-split grid ----------
// blocks [0, pB): dtype detect + weight conversion + x conversion
// blocks [pB, pB+cB): per-edge degree count via global atomics on cnt[]
// (cnt zeroed by hipMemsetAsync before this kernel). Count role self-detects
// int64 (reads first 256 odd words) -> no dependency on flags.
__global__ __launch_bounds__(256) void prep_count_kernel(
    const unsigned short* __restrict__ xh, const int* __restrict__ ei32,
    const void* __restrict__ w1a, const void* __restrict__ w1r,
    const void* __restrict__ b1,  const void* __restrict__ w2a,
    const void* __restrict__ w2r, const void* __restrict__ b2,
    const void* __restrict__ wl,  const void* __restrict__ bl,
    float* __restrict__ wbuf, unsigned short* __restrict__ Wt,
    int* __restrict__ flags, const void* __restrict__ x_in,
    unsigned short* __restrict__ x16, int n8,
    int* __restrict__ cnt_g, int E, int N, int pB) {
    __shared__ int cnt_bf, cnt_nz;
    int tid = threadIdx.x;

    if (blockIdx.x >= pB) {
        // ---- count role ----
        int c = blockIdx.x - pB;
        if (tid == 0) cnt_nz = 0;
        __syncthreads();
        if (ei32[tid * 2 + 1] != 0) atomicAdd(&cnt_nz, 1);
        __syncthreads();
        int idx64 = (cnt_nz < 8) ? 1 : 0;
        long base = (long)c * CHUNK;
#pragma unroll 4
        for (int j = 0; j < CHUNK / 256; ++j) {
            long e = base + j * 256 + tid;
            if (e < E) {
                int d = idx64 ? ei32[2 * ((long)E + e)] : ei32[(long)E + e];
                if ((unsigned)d < (unsigned)N)
                    atomicAdd(&cnt_g[d], 1);
            }
        }
        return;
    }

    // ---- prep role ----
    if (tid == 0) { cnt_bf = 0; cnt_nz = 0; }
    __syncthreads();
    unsigned short h = xh[tid * 2];
    int e = (h >> 7) & 0xFF;
    if (e >= 110 && e <= 132) atomicAdd(&cnt_bf, 1);
    if (ei32[tid * 2 + 1] != 0) atomicAdd(&cnt_nz, 1);
    __syncthreads();
    int f0 = (cnt_bf >= 128) ? 1 : 0;
    if (blockIdx.x == 0 && tid == 0) {
        flags[0] = f0;
        flags[1] = (cnt_nz < 8) ? 1 : 0;
    }
    int i = blockIdx.x * 256 + tid;
    // weights (blocks 0..65): wbuf f32 + Wt bf16-transposed
    if (i < 16642) {
        const void* src; int off;
        if      (i < 4096)  { src = w1a; off = i; }
        else if (i < 8192)  { src = w1r; off = i - 4096; }
        else if (i < 8256)  { src = b1;  off = i - 8192; }
        else if (i < 12352) { src = w2a; off = i - 8256; }
        else if (i < 16448) { src = w2r; off = i - 12352; }
        else if (i < 16512) { src = b2;  off = i - 16448; }
        else if (i < 16640) { src = wl;  off = i - 16512; }
        else                { src = bl;  off = i - 16640; }
        float v = f0 ? bflo2f(((const unsigned short*)src)[off])
                     : ((const float*)src)[off];
        wbuf[i] = v;
        unsigned short hv = f2bf(v);   // exact round-trip when input was bf16
        if (i < 4096)                      Wt[(off & 63) * 128 + (off >> 6)] = hv;
        else if (i < 8192)                 Wt[(off & 63) * 128 + 64 + (off >> 6)] = hv;
        else if (i >= 8256 && i < 12352)   Wt[8192 + (off & 63) * 128 + (off >> 6)] = hv;
        else if (i >= 12352 && i < 16448)  Wt[8192 + (off & 63) * 128 + 64 + (off >> 6)] = hv;
    }
    // x -> bf16 (fp32 path only)
    if (!f0 && i < n8) {
        float4 a = ((const float4*)x_in)[2 * i];
        float4 b = ((const float4*)x_in)[2 * i + 1];
        uint4 o;
        o.x = (unsigned int)f2bf(a.x) | ((unsigned int)f2bf(a.y) << 16);
        o.y = (unsigned int)f2bf(a.z) | ((unsigned int)f2bf(a.w) << 16);
        o.z = (unsigned int)f2bf(b.x) | ((unsigned int)f2bf(b.y) << 16);
        o.w = (unsigned int)f2bf(b.z) | ((unsigned int)f2bf(b.w) << 16);
        ((uint4*)x16)[i] = o;
    }
}

// ---------- scan over cnt[0..N): offs = exclusive prefix sum ----------
__global__ __launch_bounds__(256) void scan1_kernel(const int* __restrict__ in,
                                                    int* __restrict__ out,
                                                    int* __restrict__ blocksum, int n) {
    int tid = threadIdx.x;
    int base = blockIdx.x * 2048 + tid * 8;
    int v[8];
    int tsum = 0;
#pragma unroll
    for (int i = 0; i < 8; ++i) {
        v[i] = (base + i < n) ? in[base + i] : 0;
        tsum += v[i];
    }
    int lane = tid & 63;
    int x = tsum;
#pragma unroll
    for (int off = 1; off < 64; off <<= 1) {
        int y = __shfl_up(x, off);
        if (lane >= off) x += y;
    }
    __shared__ int wsum[4];
    int wave = tid >> 6;
    if (lane == 63) wsum[wave] = x;
    __syncthreads();
    int woff = 0;
#pragma unroll
    for (int w = 0; w < 4; ++w) if (w < wave) woff += wsum[w];
    int run = woff + x - tsum;
#pragma unroll
    for (int i = 0; i < 8; ++i) {
        if (base + i < n) out[base + i] = run;
        run += v[i];
    }
    if (tid == 255) blocksum[blockIdx.x] = woff + x;
}

// scan3: add block prefix (one LDS reduce per block) and materialize head=offs.
__global__ __launch_bounds__(256) void scan3_kernel(int* __restrict__ out,
                                                    int* __restrict__ head,
                                                    const int* __restrict__ blocksum, int n) {
    int bb = blockIdx.x, tid = threadIdx.x;
    __shared__ int wsum[4];
    __shared__ int spre;
    int s = 0;
    for (int b = tid; b < bb; b += 256) s += blocksum[b];
#pragma unroll
    for (int off = 32; off > 0; off >>= 1) s += __shfl_down(s, off);
    int lane = tid & 63, wave = tid >> 6;
    if (lane == 0) wsum[wave] = s;
    __syncthreads();
    if (tid == 0) spre = wsum[0] + wsum[1] + wsum[2] + wsum[3];
    __syncthreads();
    int pre = spre;
    int base = bb * 2048;
#pragma unroll
    for (int k = 0; k < 8; ++k) {
        int i = base + k * 256 + tid;
        if (i < n) {
            int v = out[i] + pre;
            out[i] = v;
            head[i] = v;
        }
    }
}

// ---------- scatter: direct CSR placement via global atomic heads ----------
// pos = atomicAdd(&head[d],1); srcs[pos] = s. Within-node order is arbitrary —
// same non-determinism class as the old p4 (its lheads atomicAdd), which passed
// at absmax 0.015625 for 6 rounds. Replaces p3+p4 (saves bkt 12.8 MB w+r and a
// full extra pass over all edges) and hist/hscan entirely.
__global__ __launch_bounds__(256) void scatter_kernel(
    const int* __restrict__ ei32, int* __restrict__ head,
    int* __restrict__ srcs, int E, int N, const int* __restrict__ flags) {
    int idx64 = flags[1];
    long stride = (long)gridDim.x * 256;
    for (long e = (long)blockIdx.x * 256 + threadIdx.x; e < E; e += stride) {
        int s = idx64 ? ei32[2 * e]             : ei32[e];
        int d = idx64 ? ei32[2 * ((long)E + e)] : ei32[(long)E + e];
        if ((unsigned)d < (unsigned)N) {
            if ((unsigned)s >= (unsigned)N) s = 0;   // clamp (memory safety)
            int pos = atomicAdd(&head[d], 1);
            srcs[pos] = s;
        }
    }
}

// ---------- 5+6 FUSED: aggregate + MFMA SAGE GEMM (one block = 64 nodes) ----------
// R5-exact (best measured): R1 gather (single node per 8-lane group, srcs
// global broadcast, unroll-4) + root half read directly from global in the
// MFMA loop (no root staging; A_l [64][72]; LDS 26624 B -> 6 blocks/CU).
// Gather is memory-system-bound (~82 MB L2-miss at ~1.8 TB/s across R1/R2/R5
// variants) — occupancy/ILP perturbations measured neutral-to-negative.
__global__ __launch_bounds__(256) void sage_fused_kernel(
    const void* __restrict__ feat_raw, const unsigned short* __restrict__ feat_ws,
    const int* __restrict__ srcs, const int* __restrict__ offs,
    const int* __restrict__ cnt,
    const unsigned short* __restrict__ Wt, const float* __restrict__ bias,
    unsigned short* __restrict__ out16, int N,
    const float* __restrict__ wl, const float* __restrict__ bl,
    void* __restrict__ out_final, const int* __restrict__ flags, int sel) {

    const unsigned short* feat16 =
        (sel && !flags[0]) ? feat_ws : (const unsigned short*)feat_raw;

    __shared__ unsigned short A_l[64][72];    // agg half only; reused as C staging
    __shared__ unsigned short B_l[64][136];   // Wt[n][k]

    int tid = threadIdx.x;
    int blk = blockIdx.x;

    // stage B: 1024 chunks of 8 shorts (B is 64 rows x 128 k)
#pragma unroll
    for (int i = 0; i < 4; ++i) {
        int ch = tid + i * 256;
        int n = ch >> 4, kc = ch & 15;
        *(uint4*)&B_l[n][kc * 8] = *(const uint4*)(Wt + n * 128 + kc * 8);
    }

    int lane = tid & 63;
    int wave = tid >> 6;
    int g = lane >> 3;
    int li = lane & 7;

    // gather-aggregate into A_l cols 0..63 (2 passes of 32 nodes)
    for (int pass = 0; pass < 2; ++pass) {
        int r = pass * 32 + wave * 8 + g;
        int node = blk * 64 + r;
        f32x2 a0 = {0.f, 0.f}, a1 = a0, a2 = a0, a3 = a0;
        int deg = 0;
        if (node < N) {
            int start = offs[node];
            deg = cnt[node];
            int j = 0;
            for (; j + 4 <= deg; j += 4) {
                int s0 = srcs[start + j];
                int s1 = srcs[start + j + 1];
                int s2 = srcs[start + j + 2];
                int s3 = srcs[start + j + 3];
                uint4 u0 = *(const uint4*)(feat16 + (size_t)s0 * FEAT + 8 * li);
                uint4 u1 = *(const uint4*)(feat16 + (size_t)s1 * FEAT + 8 * li);
                uint4 u2 = *(const uint4*)(feat16 + (size_t)s2 * FEAT + 8 * li);
                uint4 u3 = *(const uint4*)(feat16 + (size_t)s3 * FEAT + 8 * li);
                a0 += bfpair(u0.x); a1 += bfpair(u0.y); a2 += bfpair(u0.z); a3 += bfpair(u0.w);
                a0 += bfpair(u1.x); a1 += bfpair(u1.y); a2 += bfpair(u1.z); a3 += bfpair(u1.w);
                a0 += bfpair(u2.x); a1 += bfpair(u2.y); a2 += bfpair(u2.z); a3 += bfpair(u2.w);
                a0 += bfpair(u3.x); a1 += bfpair(u3.y); a2 += bfpair(u3.z); a3 += bfpair(u3.w);
            }
            for (; j < deg; ++j) {
                int s = srcs[start + j];
                uint4 u = *(const uint4*)(feat16 + (size_t)s * FEAT + 8 * li);
                a0 += bfpair(u.x); a1 += bfpair(u.y); a2 += bfpair(u.z); a3 += bfpair(u.w);
            }
        }
        float inv = 1.0f / (float)(deg > 0 ? deg : 1);
        uint4 o;
        o.x = (unsigned)f2bf(a0.x * inv) | ((unsigned)f2bf(a0.y * inv) << 16);
        o.y = (unsigned)f2bf(a1.x * inv) | ((unsigned)f2bf(a1.y * inv) << 16);
        o.z = (unsigned)f2bf(a2.x * inv) | ((unsigned)f2bf(a2.y * inv) << 16);
        o.w = (unsigned)f2bf(a3.x * inv) | ((unsigned)f2bf(a3.y * inv) << 16);
        *(uint4*)&A_l[r][8 * li] = o;
    }
    __syncthreads();

    int r0 = wave * 16;
    int m = lane & 15, quad = lane >> 4;

    // root row for the k0>=64 fragments: direct global load, clamped
    int arow = blk * 64 + r0 + m;
    if (arow >= N) arow = 0;
    const unsigned short* rootp = feat16 + (size_t)arow * FEAT + quad * 8;

    f32x4 acc0 = {0.f, 0.f, 0.f, 0.f};
    f32x4 acc1 = acc0, acc2 = acc0, acc3 = acc0;

#pragma unroll
    for (int k0 = 0; k0 < 128; k0 += 32) {
        bf16x8 a;
        if (k0 < 64) a = *(const bf16x8*)&A_l[r0 + m][k0 + quad * 8];
        else         a = *(const bf16x8*)(rootp + (k0 - 64));
        bf16x8 b0 = *(const bf16x8*)&B_l[ 0 + m][k0 + quad * 8];
        bf16x8 b1 = *(const bf16x8*)&B_l[16 + m][k0 + quad * 8];
        bf16x8 b2 = *(const bf16x8*)&B_l[32 + m][k0 + quad * 8];
        bf16x8 b3 = *(const bf16x8*)&B_l[48 + m][k0 + quad * 8];
        acc0 = __builtin_amdgcn_mfma_f32_16x16x32_bf16(a, b0, acc0, 0, 0, 0);
        acc1 = __builtin_amdgcn_mfma_f32_16x16x32_bf16(a, b1, acc1, 0, 0, 0);
        acc2 = __builtin_amdgcn_mfma_f32_16x16x32_bf16(a, b2, acc2, 0, 0, 0);
        acc3 = __builtin_amdgcn_mfma_f32_16x16x32_bf16(a, b3, acc3, 0, 0, 0);
    }
    __syncthreads();   // done reading A_l; reuse as C staging

    // epilogue: +bias, relu, bf16 -> A_l[row][col]  (C/D: col=lane&15, row=quad*4+reg)
#pragma unroll
    for (int c = 0; c < 4; ++c) {
        f32x4 av = (c == 0) ? acc0 : (c == 1) ? acc1 : (c == 2) ? acc2 : acc3;
        float bv = bias[c * 16 + m];
#pragma unroll
        for (int reg = 0; reg < 4; ++reg) {
            float v = fmaxf(av[reg] + bv, 0.f);
            A_l[r0 + quad * 4 + reg][c * 16 + m] = f2bf(v);
        }
    }
    __syncthreads();

    // coalesced store of C rows (layer 1 only): 512 uint4 chunks
    if (out16) {
#pragma unroll
        for (int i = 0; i < 2; ++i) {
            int ch = tid + i * 256;
            int r = ch >> 3, c = ch & 7;
            int row = blk * 64 + r;
            if (row < N)
                ((uint4*)(out16 + (size_t)row * FEAT))[c] = *(const uint4*)&A_l[r][c * 8];
        }
    }

    // fused final projection (layer 2): 4 threads per row, 16 feats each
    if (wl) {
        int r = tid >> 2, part = tid & 3;
        int row = blk * 64 + r;
        if (row < N) {
            float p0 = 0.f, p1 = 0.f;
#pragma unroll
            for (int j = 0; j < 16; ++j) {
                int f = part * 16 + j;
                float v = bflo2f(A_l[r][f]);
                p0 += v * wl[f * 2 + 0];
                p1 += v * wl[f * 2 + 1];
            }
            p0 += __shfl_down(p0, 2, 4); p0 += __shfl_down(p0, 1, 4);
            p1 += __shfl_down(p1, 2, 4); p1 += __shfl_down(p1, 1, 4);
            if (part == 0) {
                p0 += bl[0];
                p1 += bl[1];
                if (flags[0]) {
                    unsigned int o = ((unsigned int)f2bf(p1) << 16) | (unsigned int)f2bf(p0);
                    ((unsigned int*)out_final)[row] = o;
                } else {
                    ((float2*)out_final)[row] = make_float2(p0, p1);
                }
            }
        }
    }
}

extern "C" void kernel_launch(void* const* d_in, const int* in_sizes, int n_in,
                              void* d_out, int out_size, void* d_ws, size_t ws_size,
                              hipStream_t stream) {
    const void* x_in = d_in[0];
    const int*  ei32 = (const int*)d_in[1];

    int N = in_sizes[0] / FEAT;
    int E = in_sizes[1] / 2;

    // workspace layout (bkt/hist/hscan gone)
    unsigned short* x16   = (unsigned short*)d_ws;                 // N*64 bf16
    unsigned short* h16   = x16 + (size_t)N * FEAT;                // N*64
    unsigned short* Wt    = h16 + (size_t)N * FEAT;                // 16384
    float*          wbuf  = (float*)(Wt + 16384);                  // 16704
    int*            flags = (int*)(wbuf + 16704);                  // 16
    int*            bsum  = flags + 16;                            // <=1024
    int*            cnt   = bsum + 1024;                           // N
    int*            offs  = cnt + N;                               // N
    int*            head  = offs + N;                              // N
    int*            srcs  = head + N;                              // E

    float* b1_32 = wbuf + 8192;
    float* b2_32 = wbuf + 16448;
    float* wl32  = wbuf + 16512;
    float* bl32  = wbuf + 16640;

    // 0. zero degree counters (graph-capturable stream op)
    hipMemsetAsync(cnt, 0, (size_t)N * sizeof(int), stream);

    // 1. prep + count merged (role-split grid)
    int n8 = N * FEAT / 8;
    int pBlocks = (n8 + 255) / 256;
    if (pBlocks < 66) pBlocks = 66;
    int cB = (E + CHUNK - 1) / CHUNK;
    prep_count_kernel<<<pBlocks + cB, 256, 0, stream>>>(
        (const unsigned short*)x_in, ei32,
        d_in[2], d_in[3], d_in[4], d_in[5], d_in[6], d_in[7], d_in[8], d_in[9],
        wbuf, Wt, flags, x_in, x16, n8,
        cnt, E, N, pBlocks);

    // 2. scan (cnt -> offs, head)
    int sB = (N + 2047) / 2048;
    scan1_kernel<<<sB, 256, 0, stream>>>(cnt, offs, bsum, N);
    scan3_kernel<<<sB, 256, 0, stream>>>(offs, head, bsum, N);

    // 3. scatter edges directly into CSR srcs
    int scB = (E + 255) / 256;
    if (scB > 2048) scB = 2048;
    scatter_kernel<<<scB, 256, 0, stream>>>(ei32, head, srcs, E, N, flags);

    int gBlocks = (N + 63) / 64;

    // 4. layer 1: fused aggregate + GEMM (x -> h16)
    sage_fused_kernel<<<gBlocks, 256, 0, stream>>>(
        x_in, x16, srcs, offs, cnt, Wt, b1_32, h16, N,
        nullptr, nullptr, nullptr, flags, 1);

    // 5. layer 2: fused aggregate + GEMM + final projection
    sage_fused_kernel<<<gBlocks, 256, 0, stream>>>(
        h16, h16, srcs, offs, cnt, Wt + 8192, b2_32, nullptr, N,
        wl32, bl32, d_out, flags, 0);
}